// Round 6
// baseline (230.536 us; speedup 1.0000x reference)
//
#include <hip/hip_runtime.h>
#include <hip/hip_bf16.h>

#define RANK 32
#define RES  512

typedef __attribute__((ext_vector_type(2))) float f32x2;

// pack 4 floats -> 4 fp8 e4m3 bytes (hardware cvt; roundtrip-consistent)
__device__ __forceinline__ unsigned int pack4_fp8(float a, float b, float c, float d) {
    int v = 0;
    v = __builtin_amdgcn_cvt_pk_fp8_f32(a, b, v, false);  // bytes 0,1
    v = __builtin_amdgcn_cvt_pk_fp8_f32(c, d, v, true);   // bytes 2,3
    return (unsigned int)v;
}

// Reference-exact axis coordinate: frac from UNCLAMPED floor, index clamped.
struct AxisCoord { int i0; float w; };
__device__ __forceinline__ AxisCoord axis_coord(float c) {
    float x = (c + 1.0f) * 0.5f * (float)(RES - 1);
    float fx = floorf(x);
    AxisCoord a;
    a.w  = x - fx;
    int i = (int)fx;
    a.i0 = min(max(i, 0), RES - 1);
    return a;
}

struct PlaneCoord {
    int x0, y0;
    float w00, w01, w10, w11;
};

__device__ __forceinline__ PlaneCoord make_coord(float cx, float cy) {
    AxisCoord ax = axis_coord(cx);
    AxisCoord ay = axis_coord(cy);
    PlaneCoord c;
    c.x0 = ax.i0; c.y0 = ay.i0;
    float ix = 1.0f - ax.w, iy = 1.0f - ay.w;
    c.w00 = ix * iy; c.w01 = ax.w * iy; c.w10 = ix * ay.w; c.w11 = ax.w * ay.w;
    return c;
}

// ===========================================================================
// Build: fp8 quad table. Record (plane,y0,x0) = [tap00|tap01|tap10|tap11],
// each tap = 32 fp8 channels (32 B) -> 128-B record = exactly one L2 line.
// (Round-2 kernel, verified correct.)
// ===========================================================================
__global__ __launch_bounds__(256) void build_quads_kernel(
    const float* __restrict__ gxy, const float* __restrict__ gxz,
    const float* __restrict__ gyz, unsigned int* __restrict__ qout)
{
    __shared__ unsigned int lds[2][RES][RANK / 4];   // 32 KB

    int bid   = blockIdx.x;
    int plane = bid >> 9;
    int y0    = bid & (RES - 1);
    const float* g = (plane == 0) ? gxy : ((plane == 1) ? gxz : gyz);
    int y1 = min(y0 + 1, RES - 1);
    int t  = threadIdx.x;
    int xa = t * 2;

    #pragma unroll
    for (int row = 0; row < 2; ++row) {
        int yy = row ? y1 : y0;
        const float* gr = g + (size_t)yy * RES + xa;
        #pragma unroll
        for (int rq = 0; rq < RANK / 4; ++rq) {
            f32x2 f0 = *reinterpret_cast<const f32x2*>(gr + (size_t)(rq * 4 + 0) * RES * RES);
            f32x2 f1 = *reinterpret_cast<const f32x2*>(gr + (size_t)(rq * 4 + 1) * RES * RES);
            f32x2 f2 = *reinterpret_cast<const f32x2*>(gr + (size_t)(rq * 4 + 2) * RES * RES);
            f32x2 f3 = *reinterpret_cast<const f32x2*>(gr + (size_t)(rq * 4 + 3) * RES * RES);
            lds[row][xa    ][rq] = pack4_fp8(f0.x, f1.x, f2.x, f3.x);
            lds[row][xa + 1][rq] = pack4_fp8(f0.y, f1.y, f2.y, f3.y);
        }
    }
    __syncthreads();

    #pragma unroll
    for (int k = 0; k < 2; ++k) {
        int xr = t + k * 256;
        int x1 = min(xr + 1, RES - 1);
        uint4* dst = reinterpret_cast<uint4*>(qout) +
                     ((size_t)plane * RES * RES + (size_t)y0 * RES + xr) * 8;
        const unsigned int* t00 = lds[0][xr];
        const unsigned int* t01 = lds[0][x1];
        const unsigned int* t10 = lds[1][xr];
        const unsigned int* t11 = lds[1][x1];
        uint4 u;
        u.x = t00[0]; u.y = t00[1]; u.z = t00[2]; u.w = t00[3]; dst[0] = u;
        u.x = t00[4]; u.y = t00[5]; u.z = t00[6]; u.w = t00[7]; dst[1] = u;
        u.x = t01[0]; u.y = t01[1]; u.z = t01[2]; u.w = t01[3]; dst[2] = u;
        u.x = t01[4]; u.y = t01[5]; u.z = t01[6]; u.w = t01[7]; dst[3] = u;
        u.x = t10[0]; u.y = t10[1]; u.z = t10[2]; u.w = t10[3]; dst[4] = u;
        u.x = t10[4]; u.y = t10[5]; u.z = t10[6]; u.w = t10[7]; dst[5] = u;
        u.x = t11[0]; u.y = t11[1]; u.z = t11[2]; u.w = t11[3]; dst[6] = u;
        u.x = t11[4]; u.y = t11[5]; u.z = t11[6]; u.w = t11[7]; dst[7] = u;
    }
}

// ---------------------------------------------------------------------------
// Decode one plane for point `lane` from staged LDS records.
// Record = 8 chunks of 16 B: chunks (0,1)=tap00, (2,3)=tap01, (4,5)=tap10,
// (6,7)=tap11; even chunk = ch0..15, odd = ch16..31. Physical slot of global
// chunk jj for record p is jj ^ (p&7)  (matches the write-side swizzle).
// ---------------------------------------------------------------------------
__device__ __forceinline__ void decode_quad(const uint4* __restrict__ stage,
                                            int c, int lane,
                                            float w00, float w01, float w10, float w11,
                                            f32x2* __restrict__ v)
{
    const float wt[4] = { w00, w01, w10, w11 };
    #pragma unroll
    for (int jj = 0; jj < 8; ++jj) {
        uint4 q = stage[(c * 64 + lane) * 8 + (jj ^ (lane & 7))];
        float wk = wt[jj >> 1];
        int vb = (jj & 1) * 8;
        unsigned int w_[4] = { q.x, q.y, q.z, q.w };
        #pragma unroll
        for (int d = 0; d < 4; ++d) {
            f32x2 lo = __builtin_amdgcn_cvt_pk_f32_fp8((int)w_[d], false);
            f32x2 hi = __builtin_amdgcn_cvt_pk_f32_fp8((int)w_[d], true);
            int k0 = vb + d * 2, k1 = k0 + 1;
            if (jj < 2) {           // tap00 initializes
                v[k0].x = wk * lo.x; v[k0].y = wk * lo.y;
                v[k1].x = wk * hi.x; v[k1].y = wk * hi.y;
            } else {
                v[k0].x = fmaf(wk, lo.x, v[k0].x);
                v[k0].y = fmaf(wk, lo.y, v[k0].y);
                v[k1].x = fmaf(wk, hi.x, v[k1].x);
                v[k1].y = fmaf(wk, hi.y, v[k1].y);
            }
        }
    }
}

// register-path variant (fallback when global_load_lds is unavailable)
__device__ __forceinline__ void decode_quad_reg(const uint4 q[8],
                                                float w00, float w01, float w10, float w11,
                                                f32x2* __restrict__ v)
{
    const float wt[4] = { w00, w01, w10, w11 };
    #pragma unroll
    for (int jj = 0; jj < 8; ++jj) {
        float wk = wt[jj >> 1];
        int vb = (jj & 1) * 8;
        unsigned int w_[4] = { q[jj].x, q[jj].y, q[jj].z, q[jj].w };
        #pragma unroll
        for (int d = 0; d < 4; ++d) {
            f32x2 lo = __builtin_amdgcn_cvt_pk_f32_fp8((int)w_[d], false);
            f32x2 hi = __builtin_amdgcn_cvt_pk_f32_fp8((int)w_[d], true);
            int k0 = vb + d * 2, k1 = k0 + 1;
            if (jj < 2) {
                v[k0].x = wk * lo.x; v[k0].y = wk * lo.y;
                v[k1].x = wk * hi.x; v[k1].y = wk * hi.y;
            } else {
                v[k0].x = fmaf(wk, lo.x, v[k0].x);
                v[k0].y = fmaf(wk, lo.y, v[k0].y);
                v[k1].x = fmaf(wk, hi.x, v[k1].x);
                v[k1].y = fmaf(wk, hi.y, v[k1].y);
            }
        }
    }
}

// ===========================================================================
// Sampler: 1 wave per block, 64 points, 3 records (xy,xz,yz) per point.
// Cooperative loads: 8 lanes fetch one 128-B record = exactly one L2 line;
// 24 global_load_lds per wave (8 records each). Chunk order pre-swizzled on
// the GLOBAL address (slot s of record p holds chunk s^(p&7)) so the
// ds_read_b128 read-back spreads 8 lanes per bank-quad = conflict-free floor.
// Staged vmcnt drains overlap xz/yz latency under xy decode.
// ===========================================================================
__global__ __launch_bounds__(64) void sample_quad_kernel(
    const float* __restrict__ pts, const unsigned char* __restrict__ table,
    const float* __restrict__ aabb, float* __restrict__ out)
{
    __shared__ __align__(16) uint4 stage[3 * 64 * 8];   // 24576 B

    int lane = threadIdx.x;
    int idx  = blockIdx.x * 64 + lane;

    float px = pts[idx * 3 + 0];
    float py = pts[idx * 3 + 1];
    float pz = pts[idx * 3 + 2];

    float lox = aabb[0], loy = aabb[1], loz = aabb[2];
    float hix = aabb[3], hiy = aabb[4], hiz = aabb[5];

    float pnx = (px - lox) * (2.0f / (hix - lox)) - 1.0f;
    float pny = (py - loy) * (2.0f / (hiy - loy)) - 1.0f;
    float pnz = (pz - loz) * (2.0f / (hiz - loz)) - 1.0f;

    PlaneCoord cxy = make_coord(pnx, pny);   // (x, y)
    PlaneCoord cxz = make_coord(pnx, pnz);   // (x, z)
    PlaneCoord cyz = make_coord(pny, pnz);   // (y, z)

    int offs[3];
    offs[0] = ((0 * RES + cxy.y0) * RES + cxy.x0) * 128;
    offs[1] = ((1 * RES + cxz.y0) * RES + cxz.x0) * 128;
    offs[2] = ((2 * RES + cyz.y0) * RES + cyz.x0) * 128;

    int p_sub = lane >> 3;               // which record within the batch of 8
    int sw    = (lane & 7) ^ p_sub;      // global chunk this lane fetches

#if __has_builtin(__builtin_amdgcn_global_load_lds)
    #pragma unroll
    for (int i = 0; i < 24; ++i) {
        const int c = i >> 3;            // class: 0=xy 1=xz 2=yz
        const int b = i & 7;             // batch of 8 records
        int p = b * 8 + p_sub;           // point whose record this lane helps
        unsigned int off = (unsigned int)__shfl(offs[c], p);
        const unsigned char* gp = table + off + sw * 16;
        unsigned int* lp = (unsigned int*)&stage[(c * 64 + b * 8) * 8];
        __builtin_amdgcn_global_load_lds(
            (const __attribute__((address_space(1))) unsigned int*)gp,
            (__attribute__((address_space(3))) unsigned int*)lp, 16, 0, 0);
        if ((i & 7) == 7) __builtin_amdgcn_sched_barrier(0);  // pin class order
    }

    f32x2 pa[16], pb[16];
    asm volatile("s_waitcnt vmcnt(16)" ::: "memory");   // xy records landed
    decode_quad(stage, 0, lane, cxy.w00, cxy.w01, cxy.w10, cxy.w11, pa);
    asm volatile("s_waitcnt vmcnt(8)" ::: "memory");    // xz landed
    decode_quad(stage, 1, lane, cxz.w00, cxz.w01, cxz.w10, cxz.w11, pb);
    #pragma unroll
    for (int k = 0; k < 16; ++k) { pa[k].x *= pb[k].x; pa[k].y *= pb[k].y; }
    asm volatile("s_waitcnt vmcnt(0)" ::: "memory");    // yz landed
    decode_quad(stage, 2, lane, cyz.w00, cyz.w01, cyz.w10, cyz.w11, pb);
#else
    // Per-lane register path: each lane loads its own 3 records.
    uint4 qa[8], qb[8], qc[8];
    #pragma unroll
    for (int i = 0; i < 8; ++i) qa[i] = *reinterpret_cast<const uint4*>(table + offs[0] + i * 16);
    #pragma unroll
    for (int i = 0; i < 8; ++i) qb[i] = *reinterpret_cast<const uint4*>(table + offs[1] + i * 16);
    #pragma unroll
    for (int i = 0; i < 8; ++i) qc[i] = *reinterpret_cast<const uint4*>(table + offs[2] + i * 16);
    f32x2 pa[16], pb[16];
    decode_quad_reg(qa, cxy.w00, cxy.w01, cxy.w10, cxy.w11, pa);
    decode_quad_reg(qb, cxz.w00, cxz.w01, cxz.w10, cxz.w11, pb);
    #pragma unroll
    for (int k = 0; k < 16; ++k) { pa[k].x *= pb[k].x; pa[k].y *= pb[k].y; }
    decode_quad_reg(qc, cyz.w00, cyz.w01, cyz.w10, cyz.w11, pb);
#endif

    float sx = 0.0f, sy = 0.0f;
    #pragma unroll
    for (int k = 0; k < 16; ++k) {
        sx = fmaf(pa[k].x, pb[k].x, sx);
        sy = fmaf(pa[k].y, pb[k].y, sy);
    }
    out[idx] = expf((sx + sy) * (1.0f / (float)RANK));
}

// ===========================================================================
// FALLBACK: direct fp32 sampling (tiny ws or odd npts) — known correct.
// ===========================================================================
__global__ __launch_bounds__(256) void sample_direct_kernel(
    const float* __restrict__ pts,
    const float* __restrict__ gxy, const float* __restrict__ gxz,
    const float* __restrict__ gyz,
    const float* __restrict__ aabb, float* __restrict__ out, int npts)
{
    int idx = blockIdx.x * 256 + threadIdx.x;
    if (idx >= npts) return;

    float px = pts[idx * 3 + 0];
    float py = pts[idx * 3 + 1];
    float pz = pts[idx * 3 + 2];

    float lox = aabb[0], loy = aabb[1], loz = aabb[2];
    float hix = aabb[3], hiy = aabb[4], hiz = aabb[5];

    float pnx = (px - lox) * (2.0f / (hix - lox)) - 1.0f;
    float pny = (py - loy) * (2.0f / (hiy - loy)) - 1.0f;
    float pnz = (pz - loz) * (2.0f / (hiz - loz)) - 1.0f;

    AxisCoord ax = axis_coord(pnx);
    AxisCoord ay = axis_coord(pny);
    AxisCoord az = axis_coord(pnz);
    int ax1 = min(ax.i0 + 1, RES - 1);
    int ay1 = min(ay.i0 + 1, RES - 1);
    int az1 = min(az.i0 + 1, RES - 1);

    float axw = ax.w, ayw = ay.w, azw = az.w;

    int o_xy00 = ay.i0 * RES + ax.i0, o_xy01 = ay.i0 * RES + ax1;
    int o_xy10 = ay1  * RES + ax.i0, o_xy11 = ay1  * RES + ax1;
    int o_xz00 = az.i0 * RES + ax.i0, o_xz01 = az.i0 * RES + ax1;
    int o_xz10 = az1  * RES + ax.i0, o_xz11 = az1  * RES + ax1;
    int o_yz00 = az.i0 * RES + ay.i0, o_yz01 = az.i0 * RES + ay1;
    int o_yz10 = az1  * RES + ay.i0, o_yz11 = az1  * RES + ay1;

    float sum = 0.0f;
    for (int r = 0; r < RANK; ++r) {
        size_t pbs = (size_t)r * RES * RES;
        float vxy = (1-axw)*(1-ayw)*gxy[pbs+o_xy00] + axw*(1-ayw)*gxy[pbs+o_xy01]
                  + (1-axw)*ayw   *gxy[pbs+o_xy10] + axw*ayw   *gxy[pbs+o_xy11];
        float vxz = (1-axw)*(1-azw)*gxz[pbs+o_xz00] + axw*(1-azw)*gxz[pbs+o_xz01]
                  + (1-axw)*azw   *gxz[pbs+o_xz10] + axw*azw   *gxz[pbs+o_xz11];
        float vyz = (1-ayw)*(1-azw)*gyz[pbs+o_yz00] + ayw*(1-azw)*gyz[pbs+o_yz01]
                  + (1-ayw)*azw   *gyz[pbs+o_yz10] + ayw*azw   *gyz[pbs+o_yz11];
        sum += vxy * vxz * vyz;
    }
    out[idx] = expf(sum * (1.0f / (float)RANK));
}

extern "C" void kernel_launch(void* const* d_in, const int* in_sizes, int n_in,
                              void* d_out, int out_size, void* d_ws, size_t ws_size,
                              hipStream_t stream) {
    const float* pts  = (const float*)d_in[0];
    const float* gxy  = (const float*)d_in[1];
    const float* gxz  = (const float*)d_in[2];
    const float* gyz  = (const float*)d_in[3];
    const float* aabb = (const float*)d_in[4];
    float* out = (float*)d_out;

    int npts = in_sizes[0] / 3;

    size_t need_quad = (size_t)3 * RES * RES * 128;   // 96 MiB

    if (ws_size >= need_quad && (npts % 64) == 0) {
        unsigned int* tbl = (unsigned int*)d_ws;
        build_quads_kernel<<<3 * RES, 256, 0, stream>>>(gxy, gxz, gyz, tbl);
        sample_quad_kernel<<<npts / 64, 64, 0, stream>>>(
            pts, (const unsigned char*)tbl, aabb, out);
    } else {
        int nblk = (npts + 255) / 256;
        sample_direct_kernel<<<nblk, 256, 0, stream>>>(pts, gxy, gxz, gyz, aabb, out, npts);
    }
}